// Round 5
// baseline (187.092 us; speedup 1.0000x reference)
//
#include <hip/hip_runtime.h>
#include <stdint.h>

typedef unsigned long long u64;

#define PADW 134
#define WPR 3                        // 3 u64 words per 134-voxel row
#define ROWS_PER_B (PADW * PADW)     // 17,956 rows per batch
#define WPB (ROWS_PER_B * WPR)       // 53,868 words per batch
#define NBATCH 2
#define NROWS (NBATCH * ROWS_PER_B)  // 35,912
#define NWORDS (NBATCH * WPB)        // 107,736
#define NV 128
#define NV3 (NV * NV * NV)
#define PAD 3

// Bit i of word j in row (z,y) = voxel x = j*64+i. Invariant: all STORED buffers
// (X, E*, sk*) have invalid bits (word 2 bits 6..63) == 0.

__device__ __forceinline__ bool inR(int v) { return (unsigned)v < (unsigned)PADW; }

__device__ __forceinline__ void loadRow(const u64* __restrict__ B, int z, int y, u64 r[3]) {
  const u64* p = B + (z * PADW + y) * WPR;
  r[0] = p[0]; r[1] = p[1]; r[2] = p[2];
}

// d |= horizontal 3-dilation of row r (OOB x -> 0, OR identity)
__device__ __forceinline__ void orHdil(const u64 r[3], u64 d[3]) {
  d[0] |= r[0] | (r[0] << 1) | ((r[0] >> 1) | (r[1] << 63));
  d[1] |= r[1] | ((r[1] << 1) | (r[0] >> 63)) | ((r[1] >> 1) | (r[2] << 63));
  d[2] |= r[2] | ((r[2] << 1) | (r[1] >> 63)) | (r[2] >> 1);
}

// e = horizontal 3-erosion of row c (OOB x -> 1, AND identity).
// e inherits c's zero invalid bits.
__device__ __forceinline__ void eroX(const u64 c[3], u64 e[3]) {
  e[0] = c[0] & ((c[0] << 1) | 1ULL)        & ((c[0] >> 1) | (c[1] << 63));
  e[1] = c[1] & ((c[1] << 1) | (c[0] >> 63)) & ((c[1] >> 1) | (c[2] << 63));
  e[2] = c[2] & ((c[2] << 1) | (c[1] >> 63)) & ((c[2] >> 1) | (1ULL << 5));
}

__device__ __forceinline__ void ridDecomp(int rid, int& b, int& z, int& y) {
  b = rid / ROWS_PER_B;
  int r = rid - b * ROWS_PER_B;
  z = r / PADW;
  y = r - z * PADW;
}

// ---------------------------------------------------------------- binarize + pad + pack
__global__ void binpack_k(const float* __restrict__ logit, u64* __restrict__ X) {
  int wid = (blockIdx.x * blockDim.x + threadIdx.x) >> 6;
  int lane = threadIdx.x & 63;
  if (wid >= NROWS) return;
  int b, z, y;
  ridDecomp(wid, b, z, y);
  bool padrow = (z < PAD || z >= PAD + NV || y < PAD || y >= PAD + NV);
  const float TH = 0.84729786f;  // ln(0.7/0.3): sigmoid(l)>0.7 <=> l>TH
  u64* rowp = X + (size_t)b * WPB + (z * PADW + y) * WPR;
#pragma unroll
  for (int j = 0; j < WPR; ++j) {
    int x = j * 64 + lane;
    bool pred = false;
    if (x < PADW) {
      if (padrow || x < PAD || x >= PAD + NV) {
        pred = true;  // pad voxel = 1
      } else {
        float l = logit[(((size_t)b * NV + (z - PAD)) * NV + (y - PAD)) * NV + (x - PAD)];
        pred = l > TH;
      }
    }
    u64 w = __ballot(pred);
    if (lane == 0) rowp[j] = w;
  }
}

// ---------------------------------------------------------------- E = ero6(B), thread per row
__global__ void ero_k(const u64* __restrict__ in, u64* __restrict__ out) {
  int rid = blockIdx.x * blockDim.x + threadIdx.x;
  if (rid >= NROWS) return;
  int b, z, y;
  ridDecomp(rid, b, z, y);
  const u64* Bb = in + (size_t)b * WPB;
  u64 c[3], e[3], n[3];
  loadRow(Bb, z, y, c);
  eroX(c, e);
  if (inR(y - 1)) { loadRow(Bb, z, y - 1, n); e[0] &= n[0]; e[1] &= n[1]; e[2] &= n[2]; }
  if (inR(y + 1)) { loadRow(Bb, z, y + 1, n); e[0] &= n[0]; e[1] &= n[1]; e[2] &= n[2]; }
  if (inR(z - 1)) { loadRow(Bb, z - 1, y, n); e[0] &= n[0]; e[1] &= n[1]; e[2] &= n[2]; }
  if (inR(z + 1)) { loadRow(Bb, z + 1, y, n); e[0] &= n[0]; e[1] &= n[1]; e[2] &= n[2]; }
  u64* o = out + (size_t)b * WPB + (z * PADW + y) * WPR;
  o[0] = e[0]; o[1] = e[1]; o[2] = e[2];
}

// ---------------------------------------------------------------- init:
// sk = X & ~dil26(E1);  E2 = ero6(E1)   (cross rows reused from the dilation's 3x3)
__global__ void open_init2_k(const u64* __restrict__ X, const u64* __restrict__ E1,
                             u64* __restrict__ sk, u64* __restrict__ E2) {
  int rid = blockIdx.x * blockDim.x + threadIdx.x;
  if (rid >= NROWS) return;
  int b, z, y;
  ridDecomp(rid, b, z, y);
  size_t boff = (size_t)b * WPB;
  const u64* Eb = E1 + boff;
  u64 acc[3] = {0, 0, 0};
  u64 cc[3];
  u64 cy0[3] = {~0ULL, ~0ULL, ~0ULL}, cy1[3] = {~0ULL, ~0ULL, ~0ULL};
  u64 cz0[3] = {~0ULL, ~0ULL, ~0ULL}, cz1[3] = {~0ULL, ~0ULL, ~0ULL};
#pragma unroll
  for (int dz = -1; dz <= 1; ++dz) {
#pragma unroll
    for (int dy = -1; dy <= 1; ++dy) {
      int zz = z + dz, yy = y + dy;
      if (!inR(zz) || !inR(yy)) continue;  // OR identity
      u64 t[3];
      loadRow(Eb, zz, yy, t);
      orHdil(t, acc);
      if (dz == 0 && dy == 0) { cc[0] = t[0]; cc[1] = t[1]; cc[2] = t[2]; }
      else if (dz == 0 && dy == -1) { cy0[0] = t[0]; cy0[1] = t[1]; cy0[2] = t[2]; }
      else if (dz == 0 && dy == 1)  { cy1[0] = t[0]; cy1[1] = t[1]; cy1[2] = t[2]; }
      else if (dz == -1 && dy == 0) { cz0[0] = t[0]; cz0[1] = t[1]; cz0[2] = t[2]; }
      else if (dz == 1 && dy == 0)  { cz1[0] = t[0]; cz1[1] = t[1]; cz1[2] = t[2]; }
    }
  }
  u64 xr[3];
  loadRow(X + boff, z, y, xr);
  u64 e[3];
  eroX(cc, e);
#pragma unroll
  for (int j = 0; j < 3; ++j) e[j] &= cy0[j] & cy1[j] & cz0[j] & cz1[j];
  int rw = (z * PADW + y) * WPR;
#pragma unroll
  for (int j = 0; j < 3; ++j) {
    sk[boff + rw + j] = xr[j] & ~acc[j];  // acc junk bits killed by clean xr
    E2[boff + rw + j] = e[j];
  }
}

// ---------------------------------------------------------------- fused iteration:
// delta = E1 & ~dil26(E2); sk2 = delta | sk | (X & dil26(sk)); E3 = ero6(E2)
__global__ void update2_k(const u64* __restrict__ X, const u64* __restrict__ E1,
                          const u64* __restrict__ E2, const u64* __restrict__ sk,
                          u64* __restrict__ sk2, u64* __restrict__ E3) {
  int rid = blockIdx.x * blockDim.x + threadIdx.x;
  if (rid >= NROWS) return;
  int b, z, y;
  ridDecomp(rid, b, z, y);
  size_t boff = (size_t)b * WPB;
  const u64* Eb = E2 + boff;
  const u64* Sb = sk + boff;
  u64 acc[3] = {0, 0, 0}, dsk[3] = {0, 0, 0};
  u64 cc[3], skc[3];
  u64 cy0[3] = {~0ULL, ~0ULL, ~0ULL}, cy1[3] = {~0ULL, ~0ULL, ~0ULL};
  u64 cz0[3] = {~0ULL, ~0ULL, ~0ULL}, cz1[3] = {~0ULL, ~0ULL, ~0ULL};
#pragma unroll
  for (int dz = -1; dz <= 1; ++dz) {
#pragma unroll
    for (int dy = -1; dy <= 1; ++dy) {
      int zz = z + dz, yy = y + dy;
      if (!inR(zz) || !inR(yy)) continue;
      u64 t[3], s[3];
      loadRow(Eb, zz, yy, t);
      loadRow(Sb, zz, yy, s);
      orHdil(t, acc);
      orHdil(s, dsk);
      if (dz == 0 && dy == 0) {
        cc[0] = t[0]; cc[1] = t[1]; cc[2] = t[2];
        skc[0] = s[0]; skc[1] = s[1]; skc[2] = s[2];
      }
      else if (dz == 0 && dy == -1) { cy0[0] = t[0]; cy0[1] = t[1]; cy0[2] = t[2]; }
      else if (dz == 0 && dy == 1)  { cy1[0] = t[0]; cy1[1] = t[1]; cy1[2] = t[2]; }
      else if (dz == -1 && dy == 0) { cz0[0] = t[0]; cz0[1] = t[1]; cz0[2] = t[2]; }
      else if (dz == 1 && dy == 0)  { cz1[0] = t[0]; cz1[1] = t[1]; cz1[2] = t[2]; }
    }
  }
  u64 e1r[3], xr[3];
  loadRow(E1 + boff, z, y, e1r);
  loadRow(X + boff, z, y, xr);
  u64 e[3];
  eroX(cc, e);
#pragma unroll
  for (int j = 0; j < 3; ++j) e[j] &= cy0[j] & cy1[j] & cz0[j] & cz1[j];
  int rw = (z * PADW + y) * WPR;
#pragma unroll
  for (int j = 0; j < 3; ++j) {
    u64 delta = e1r[j] & ~acc[j];          // clean: e1r clean
    u64 s1 = (xr[j] & dsk[j]) | skc[j];    // clean: xr, skc clean
    sk2[boff + rw + j] = delta | s1;
    E3[boff + rw + j] = e[j];
  }
}

// ---------------------------------------------------------------- reduction
__global__ void reduce_k(const float* __restrict__ logit, const float* __restrict__ vcl,
                         const u64* __restrict__ S, double* __restrict__ acc) {
  int b = blockIdx.y;
  const float* lg = logit + (size_t)b * NV3;
  const float* cl = vcl + (size_t)b * NV3;
  const u64* Sb = S + (size_t)b * WPB;
  float p0 = 0.f, p1 = 0.f, p2 = 0.f, p3 = 0.f;
  for (int i = blockIdx.x * blockDim.x + threadIdx.x; i < NV3; i += gridDim.x * blockDim.x) {
    int z = i >> 14;
    int r = i & 16383;
    int y = r >> 7;
    int x = r & 127;
    float vp = 1.0f / (1.0f + expf(-lg[i]));
    float c = cl[i];
    p0 += vp * c;
    p1 += c;
    int xp = x + PAD;
    u64 w = Sb[((z + PAD) * PADW + (y + PAD)) * WPR + (xp >> 6)];
    if ((w >> (xp & 63)) & 1ULL) {
      p2 += c * vp;
      p3 += vp;
    }
  }
  for (int off = 32; off > 0; off >>= 1) {
    p0 += __shfl_down(p0, off);
    p1 += __shfl_down(p1, off);
    p2 += __shfl_down(p2, off);
    p3 += __shfl_down(p3, off);
  }
  __shared__ float s0[4], s1[4], s2[4], s3[4];
  int wid = threadIdx.x >> 6;
  int lane = threadIdx.x & 63;
  if (lane == 0) { s0[wid] = p0; s1[wid] = p1; s2[wid] = p2; s3[wid] = p3; }
  __syncthreads();
  if (threadIdx.x == 0) {
    double a0 = 0, a1 = 0, a2 = 0, a3 = 0;
    for (int w = 0; w < 4; ++w) { a0 += s0[w]; a1 += s1[w]; a2 += s2[w]; a3 += s3[w]; }
    atomicAdd(&acc[b * 4 + 0], a0);
    atomicAdd(&acc[b * 4 + 1], a1);
    atomicAdd(&acc[b * 4 + 2], a2);
    atomicAdd(&acc[b * 4 + 3], a3);
  }
}

__global__ void finalize_k(const double* __restrict__ acc, float* __restrict__ out) {
  if (threadIdx.x != 0 || blockIdx.x != 0) return;
  const double eps = 1e-12;
  double tp = 0.5 * ((acc[0] + eps) / (acc[1] + eps) + (acc[4] + eps) / (acc[5] + eps));
  double ts = 0.5 * ((acc[2] + eps) / (acc[3] + eps) + (acc[6] + eps) / (acc[7] + eps));
  double loss = 1.0 - (2.0 * tp * ts + eps) / (tp + ts + eps);
  out[0] = (float)loss;
}

// ---------------------------------------------------------------- host side
extern "C" void kernel_launch(void* const* d_in, const int* in_sizes, int n_in,
                              void* d_out, int out_size, void* d_ws, size_t ws_size,
                              hipStream_t stream) {
  const float* logit = (const float*)d_in[0];  // Vlogit
  const float* vcl = (const float*)d_in[1];    // Vcl
  // d_in[2] (Vedt) unused by the reference loss
  float* out = (float*)d_out;

  const size_t bufW = (size_t)NWORDS;
  u64* base = (u64*)d_ws;
  u64* B[7];
  for (int i = 0; i < 7; ++i) B[i] = base + (size_t)i * bufW;
  double* acc = (double*)(base + 7 * bufW);

  const int mThreads = 64;
  const int mBlocks = (NROWS + mThreads - 1) / mThreads;  // 562
  const int bBlocks = (NROWS + 3) / 4;                    // binpack: 4 waves/block

  binpack_k<<<bBlocks, 256, 0, stream>>>(logit, B[0]);

  // ---- skeletonize #1 (5 iters)
  u64 *X = B[0], *E1 = B[1], *E2 = B[2], *E3 = B[3], *sk = B[4], *sk2 = B[5];
  ero_k<<<mBlocks, mThreads, 0, stream>>>(X, E1);
  open_init2_k<<<mBlocks, mThreads, 0, stream>>>(X, E1, sk, E2);
  for (int it = 0; it < 5; ++it) {
    update2_k<<<mBlocks, mThreads, 0, stream>>>(X, E1, E2, sk, sk2, E3);
    u64* t = X; X = E1; E1 = E2; E2 = E3; E3 = t;
    t = sk; sk = sk2; sk2 = t;
  }
  u64* S1 = sk;  // binary support == clamped skel

  // ---- skeletonize #2 (2 iters) on S1; B[6] + retired buffers as scratch
  u64 *X2 = S1, *E1b = B[6], *E2b = X, *E3b = E1, *skb = E2, *sk2b = E3;
  ero_k<<<mBlocks, mThreads, 0, stream>>>(X2, E1b);
  open_init2_k<<<mBlocks, mThreads, 0, stream>>>(X2, E1b, skb, E2b);
  for (int it = 0; it < 2; ++it) {
    update2_k<<<mBlocks, mThreads, 0, stream>>>(X2, E1b, E2b, skb, sk2b, E3b);
    u64* t = X2; X2 = E1b; E1b = E2b; E2b = E3b; E3b = t;
    t = skb; skb = sk2b; sk2b = t;
  }
  u64* Sfinal = skb;

  hipMemsetAsync(acc, 0, 8 * sizeof(double), stream);
  reduce_k<<<dim3(256, 2), 256, 0, stream>>>(logit, vcl, Sfinal, acc);
  finalize_k<<<1, 64, 0, stream>>>(acc, out);
}